// Round 5
// baseline (45021.036 us; speedup 1.0000x reference)
//
#include <hip/hip_runtime.h>
#include <math.h>

#define BATCHN 32
#define SEQT   2048
#define NMELS  80
#define HIDN   512
#define NCLSN  64
#define BTROWS (BATCHN*SEQT)   // 65536
#define WUP    256
#define CHK    512
#define NQ     32              // groups: 32 batch x 4 chunks / 4 seqs each
#define PSTR   1280            // u32 stride per slice payload (1152 used)

typedef _Float16 f16x2 __attribute__((ext_vector_type(2)));
typedef unsigned long long ull;

#if defined(__has_builtin)
#if __has_builtin(__builtin_amdgcn_fdot2)
#define FDOT2(a,b,c) __builtin_amdgcn_fdot2((a),(b),(c),false)
#endif
#endif
#ifndef FDOT2
#define FDOT2(a,b,c) ((float)(a).x*(float)(b).x + (float)(a).y*(float)(b).y + (c))
#endif

__device__ inline unsigned pkf16(float a, float b){
  union { f16x2 h; unsigned u; } c;
  c.h.x = (_Float16)a; c.h.y = (_Float16)b;
  return c.u;
}
__device__ inline f16x2 uph(unsigned u){
  union { unsigned u; f16x2 h; } c; c.u = u; return c.h;
}
__device__ inline float wave_sum(float v) {
  #pragma unroll
  for (int o = 32; o > 0; o >>= 1) v += __shfl_xor(v, o, 64);
  return v;
}
__device__ inline float ftanh(float x) {
  float ax = fabsf(x);
  float e = __expf(2.0f*ax);
  float t = 1.0f - 2.0f/(e + 1.0f);
  return copysignf(t, x);
}
__device__ inline unsigned pack_bf16(float a, float b) {
  union { float f; unsigned u; } ua, ub; ua.f = a; ub.f = b;
  unsigned lo = (ua.u + 0x7fffu + ((ua.u >> 16) & 1u)) >> 16;
  unsigned hi = (ub.u + 0x7fffu + ((ub.u >> 16) & 1u)) & 0xffff0000u;
  return (lo & 0xffffu) | hi;
}
__device__ inline float bf_lo(unsigned p) { union { unsigned u; float f; } c; c.u = p << 16; return c.f; }
__device__ inline float bf_hi(unsigned p) { union { unsigned u; float f; } c; c.u = p & 0xffff0000u; return c.f; }

#define AT_ST(p,v) __hip_atomic_store((p),(v),__ATOMIC_RELAXED,__HIP_MEMORY_SCOPE_AGENT)
#define AT_LD(p)   __hip_atomic_load((p),__ATOMIC_RELAXED,__HIP_MEMORY_SCOPE_AGENT)

// ============================================================================
// PREP (validated r3/r4): be1 (f16), xs0, xs1
// ============================================================================
#define PBM 32
__global__ __launch_bounds__(256) void prep_kernel(
    const float* __restrict__ feats, const float* __restrict__ B0,
    const float* __restrict__ B1,
    _Float16* __restrict__ be1h, float* __restrict__ xs0w, float* __restrict__ xs1w)
{
  __shared__ float fts[PBM*80];
  __shared__ _Float16 be0h[PBM*520];
  __shared__ float rxs0_s[PBM], rxs1_s[PBM];
  __shared__ float Bs[16*521];
  const int tid = threadIdx.x;
  const size_t m0 = (size_t)blockIdx.x * PBM;

  for (int i = tid; i < PBM*80; i += 256) {
    int r = i/80, k = i - r*80;
    fts[i] = feats[(m0+r)*80 + k];
  }
  __syncthreads();
  {
    int r = tid >> 3, kc = tid & 7;
    float s = 0.f;
    for (int k = kc*10; k < kc*10+10; k++) { float v = fts[r*80+k]; s += v*v; }
    s += __shfl_xor(s,1,64); s += __shfl_xor(s,2,64); s += __shfl_xor(s,4,64);
    float xs0v = fmaxf(sqrtf(s), 1e-6f);
    if (kc == 0) { xs0w[m0+r] = xs0v; rxs0_s[r] = 1.0f/xs0v; }
  }
  __syncthreads();
  {
    unsigned b0a[40], b0b[40];
    #pragma unroll
    for (int i = 0; i < 40; i++) {
      float2 v = *(const float2*)(B0 + (size_t)tid*80 + 2*i);
      b0a[i] = pkf16(v.x, v.y);
      float2 w = *(const float2*)(B0 + (size_t)(tid+256)*80 + 2*i);
      b0b[i] = pkf16(w.x, w.y);
    }
    for (int r = 0; r < PBM; r++) {
      float rx = rxs0_s[r];
      float a0 = 0.f, a1 = 0.f;
      #pragma unroll
      for (int i = 0; i < 40; i++) {
        float2 f = *(const float2*)(fts + r*80 + 2*i);
        f16x2 fa; fa.x = (_Float16)(f.x*rx); fa.y = (_Float16)(f.y*rx);
        a0 = FDOT2(uph(b0a[i]), fa, a0);
        a1 = FDOT2(uph(b0b[i]), fa, a1);
      }
      be0h[r*520 + tid]     = (_Float16)a0;
      be0h[r*520 + tid+256] = (_Float16)a1;
    }
  }
  __syncthreads();
  {
    int r = tid >> 3, kc = tid & 7;
    float s = 0.f;
    for (int k = kc*64; k < kc*64+64; k++) { float v = (float)be0h[r*520+k]; s += v*v; }
    s += __shfl_xor(s,1,64); s += __shfl_xor(s,2,64); s += __shfl_xor(s,4,64);
    float xs1v = fmaxf(sqrtf(s), 1e-6f);
    if (kc == 0) { xs1w[m0+r] = xs1v; rxs1_s[r] = 1.0f/xs1v; }
  }
  __syncthreads();
  const int tx = tid & 63, ty = tid >> 6;
  float acc[8][8] = {};
  for (int k0 = 0; k0 < 512; k0 += 16) {
    for (int nn = tid; nn < 512; nn += 256) {
      const float* src = B1 + (size_t)nn*512 + k0;
      #pragma unroll
      for (int q = 0; q < 4; q++) {
        float4 v = *(const float4*)(src + 4*q);
        Bs[(4*q+0)*521 + nn] = v.x; Bs[(4*q+1)*521 + nn] = v.y;
        Bs[(4*q+2)*521 + nn] = v.z; Bs[(4*q+3)*521 + nn] = v.w;
      }
    }
    __syncthreads();
    #pragma unroll
    for (int kk = 0; kk < 16; kk += 2) {
      float a0[8], a1[8];
      #pragma unroll
      for (int i = 0; i < 8; i++) {
        f16x2 p = *(const f16x2*)&be0h[(ty*8+i)*520 + k0 + kk];
        a0[i] = (float)p.x; a1[i] = (float)p.y;
      }
      float b0v[8], b1v[8];
      #pragma unroll
      for (int j = 0; j < 8; j++) {
        b0v[j] = Bs[kk*521 + tx*8+j];
        b1v[j] = Bs[(kk+1)*521 + tx*8+j];
      }
      #pragma unroll
      for (int i = 0; i < 8; i++)
        #pragma unroll
        for (int j = 0; j < 8; j++)
          acc[i][j] += a0[i]*b0v[j] + a1[i]*b1v[j];
    }
    __syncthreads();
  }
  #pragma unroll
  for (int i = 0; i < 8; i++) {
    int r = ty*8+i; float sc = rxs1_s[r];
    uint4 d;
    d.x = pkf16(acc[i][0]*sc, acc[i][1]*sc);
    d.y = pkf16(acc[i][2]*sc, acc[i][3]*sc);
    d.z = pkf16(acc[i][4]*sc, acc[i][5]*sc);
    d.w = pkf16(acc[i][6]*sc, acc[i][7]*sc);
    *(uint4*)(be1h + (m0+r)*512 + tx*8) = d;
  }
}

// ---- head base (validated): out = head_b + be1 @ head_w[:,512:]^T ----
__global__ __launch_bounds__(256) void headbase_kernel(
    const _Float16* __restrict__ A, const float* __restrict__ Bt,
    float* __restrict__ C, const float* __restrict__ bias)
{
  __shared__ float As[16][132];
  __shared__ float Bs[16][68];
  const int tid = threadIdx.x;
  const size_t m0 = (size_t)blockIdx.x * 128;
  const int tx = tid & 15, ty = tid >> 4;
  float acc[8][4] = {};
  for (int k0 = 0; k0 < 512; k0 += 16) {
    {
      int m = tid >> 1, kk2 = (tid*4) & 7;
      uint4 v = *(const uint4*)(A + (m0+m)*512 + k0 + kk2*2);
      f16x2 h0 = uph(v.x), h1 = uph(v.y), h2v = uph(v.z), h3 = uph(v.w);
      As[kk2*2+0][m] = (float)h0.x; As[kk2*2+1][m] = (float)h0.y;
      As[kk2*2+2][m] = (float)h1.x; As[kk2*2+3][m] = (float)h1.y;
      As[kk2*2+4][m] = (float)h2v.x; As[kk2*2+5][m] = (float)h2v.y;
      As[kk2*2+6][m] = (float)h3.x; As[kk2*2+7][m] = (float)h3.y;
    }
    {
      int n = tid >> 2, kq = tid & 3;
      float4 v = *(const float4*)(Bt + (size_t)n*1024 + k0 + kq*4);
      Bs[kq*4+0][n] = v.x; Bs[kq*4+1][n] = v.y;
      Bs[kq*4+2][n] = v.z; Bs[kq*4+3][n] = v.w;
    }
    __syncthreads();
    #pragma unroll
    for (int kk = 0; kk < 16; kk++) {
      float a[8], b[4];
      #pragma unroll
      for (int i = 0; i < 8; i++) a[i] = As[kk][ty*8+i];
      #pragma unroll
      for (int j = 0; j < 4; j++) b[j] = Bs[kk][tx*4+j];
      #pragma unroll
      for (int i = 0; i < 8; i++)
        #pragma unroll
        for (int j = 0; j < 4; j++) acc[i][j] += a[i]*b[j];
    }
    __syncthreads();
  }
  #pragma unroll
  for (int i = 0; i < 8; i++) {
    size_t m = m0 + ty*8 + i;
    float4 v;
    v.x = acc[i][0] + bias[tx*4+0];
    v.y = acc[i][1] + bias[tx*4+1];
    v.z = acc[i][2] + bias[tx*4+2];
    v.w = acc[i][3] + bias[tx*4+3];
    *(float4*)(C + m*64 + tx*4) = v;
  }
}

// ============================================================================
// RECUR v4: round-4 dataflow, but payload via LDS-staged COALESCED REGULAR
// loads/stores (RELEASE/ACQUIRE flag provides cross-XCD cache maintenance).
// Head contribution rides in the payload (f16); slice 0 sums + regular RMW.
// Payload per slice (u32 words): [0,1024): word 2k+p = pk(g partials seqs
// (2p,2p+1)) for k=word>>1; [1024,1152): head partials word 1024+j*32+c/2.
// ============================================================================
__global__ __launch_bounds__(512, 2) void recur4_kernel(
    const float* __restrict__ feats, const float* __restrict__ B0,
    const float* __restrict__ C1, const float* __restrict__ W1,
    const float* __restrict__ ltc,
    const float* __restrict__ tau0p, const float* __restrict__ gammap,
    const float* __restrict__ head_w, const _Float16* __restrict__ be1h,
    const float* __restrict__ xs0w, const float* __restrict__ xs1w,
    float* __restrict__ out, unsigned* __restrict__ P,
    unsigned* __restrict__ CNT)
{
  const int wg = blockIdx.x;
  const int x = wg & 7, u2 = wg >> 3;
  const int s = u2 & 7, qq = u2 >> 3;
  const int q = x*4 + qq;               // 8 slice-WGs of group q share blockIdx%8 (XCD heuristic)
  const int chunk = q >> 3;
  const int t_out = chunk * CHK;
  const int t_begin = (chunk == 0) ? 0 : (t_out - WUP);
  const int D = t_out + CHK - t_begin;  // 512 or 768
  const int tid = threadIdx.x;
  const int lane = tid & 63, wave = tid >> 6;
  const int row0 = s*64;

  __shared__ unsigned b0_s[512][41];        // B0 f16 pairs (84KB)
  __shared__ unsigned whh_s[64][33];        // head_w h-half slice
  __shared__ unsigned h2_s[4][32];          // own h slice, f16 pairs
  __shared__ unsigned e_s[4][256];          // full error, f16 pairs over k
  __shared__ unsigned be0_s[4][256];        // full be0, f16 pairs over k
  __shared__ __align__(16) unsigned pay_s[1152];  // outgoing payload staging
  __shared__ float fts_s[4][80];
  __shared__ float red_s[8][4][64];         // err_eff partials [oct][j][r]
  __shared__ float esw_s[8][4];
  __shared__ float sp_s[4];
  __shared__ float xs1_s[4], rxs0_s[4];

  // ---- weights to VGPRs (static indexing only) ----
  unsigned c1w[32];   // C1[tid][row0..row0+64) f16 pairs
  {
    const float* src = C1 + (size_t)tid*512 + row0;
    #pragma unroll
    for (int i = 0; i < 16; i++) {
      float4 v = *(const float4*)(src + 4*i);
      c1w[2*i] = pkf16(v.x, v.y); c1w[2*i+1] = pkf16(v.z, v.w);
    }
  }
  unsigned w1w[32];   // W1[row0+lane][wave*64 .. +64)
  {
    const float* src = W1 + (size_t)(row0 + lane)*512 + wave*64;
    #pragma unroll
    for (int i = 0; i < 16; i++) {
      float4 v = *(const float4*)(src + 4*i);
      w1w[2*i] = pkf16(v.x, v.y); w1w[2*i+1] = pkf16(v.z, v.w);
    }
  }
  {
    const float* src = B0 + (size_t)tid*80;
    #pragma unroll
    for (int i = 0; i < 20; i++) {
      float4 v = *(const float4*)(src + 4*i);
      b0_s[tid][2*i] = pkf16(v.x, v.y); b0_s[tid][2*i+1] = pkf16(v.z, v.w);
    }
  }
  if (tid < 64) {
    const float* src = head_w + (size_t)tid*1024 + row0;
    #pragma unroll
    for (int i = 0; i < 16; i++) {
      float4 v = *(const float4*)(src + 4*i);
      whh_s[tid][2*i] = pkf16(v.x, v.y); whh_s[tid][2*i+1] = pkf16(v.z, v.w);
    }
  }
  if (tid < 128) h2_s[tid>>5][tid&31] = 0u;
  float a0v = 0.f, h = 0.f;
  if (tid < 256) {
    float xv = ltc[row0 + lane];
    float spl = (xv > 20.f) ? xv : log1pf(__expf(xv));
    a0v = 0.1f/(1.0f + spl);
  }
  const float tau0v = *tau0p, gmv = *gammap;
  unsigned* cb = CNT + q*32;
  __syncthreads();

  for (int t = 0; t <= D; ++t) {
    const int gt = t_begin + t;
    const int par = t & 1;
    unsigned* Pq = P + ((size_t)par*NQ + q)*(8*PSTR);
    unsigned* Pw = Pq + (size_t)s*PSTR;
    const bool live = (t < D);

    // ---- per-step inputs ----
    if (live) {
      if (tid < 320) {
        int j = tid/80, k = tid - j*80;
        int bj = (q & 7)*4 + j;
        fts_s[j][k] = feats[((size_t)bj*SEQT + gt)*80 + k];
      }
      if (tid >= 448 && tid < 456) {
        int j = (tid - 448) & 3;
        size_t bt = (size_t)((q & 7)*4 + j)*SEQT + gt;
        if (tid < 452) rxs0_s[j] = 1.0f / xs0w[bt];
        else           xs1_s[j]  = xs1w[bt];
      }
    }
    __syncthreads();

    // ---- be0 (this thread's row, 4 seqs) + C1 column partial -> pay_s ----
    if (live) {
      float bp0=0,bp1=0,bp2=0,bp3=0;
      #pragma unroll
      for (int p = 0; p < 40; p++) {
        f16x2 w = uph(b0_s[tid][p]);
        float w0 = (float)w.x, w1v = (float)w.y;
        float2 f0 = *(const float2*)&fts_s[0][2*p];
        float2 f1 = *(const float2*)&fts_s[1][2*p];
        float2 f2 = *(const float2*)&fts_s[2][2*p];
        float2 f3 = *(const float2*)&fts_s[3][2*p];
        bp0 += w0*f0.x + w1v*f0.y; bp1 += w0*f1.x + w1v*f1.y;
        bp2 += w0*f2.x + w1v*f2.y; bp3 += w0*f3.x + w1v*f3.y;
      }
      float be0v[4] = { bp0*rxs0_s[0], bp1*rxs0_s[1], bp2*rxs0_s[2], bp3*rxs0_s[3] };
      #pragma unroll
      for (int j = 0; j < 4; j++) {
        float other = __shfl_xor(be0v[j], 1, 64);
        if (!(tid & 1)) be0_s[j][tid >> 1] = pkf16(be0v[j], other);
      }
      float pg0=0,pg1=0,pg2=0,pg3=0;
      #pragma unroll
      for (int p = 0; p < 32; p++) {
        f16x2 w = uph(c1w[p]);
        float w0 = (float)w.x, w1v = (float)w.y;
        f16x2 h0 = uph(h2_s[0][p]), h1 = uph(h2_s[1][p]);
        f16x2 h2v = uph(h2_s[2][p]), h3 = uph(h2_s[3][p]);
        pg0 += w0*(float)h0.x + w1v*(float)h0.y;
        pg1 += w0*(float)h1.x + w1v*(float)h1.y;
        pg2 += w0*(float)h2v.x + w1v*(float)h2v.y;
        pg3 += w0*(float)h3.x + w1v*(float)h3.y;
      }
      pay_s[2*tid]   = pkf16(pg0, pg1);
      pay_s[2*tid+1] = pkf16(pg2, pg3);
    }
    __syncthreads();    // pay_s complete (g this step + head from prev step)

    // ---- coalesced REGULAR payload store (288 x uint4 = 4.6KB) ----
    if (tid < 288) *(uint4*)(Pw + 4*tid) = *(const uint4*)(&pay_s[4*tid]);
    __syncthreads();    // drain vmcnt before flag (compiler emits waitcnt)

    // ---- 8-way barrier: RELEASE add (L2 wb) / ACQUIRE spin (L2 inv) ----
    if (tid == 0) {
      __hip_atomic_fetch_add(cb, 1u, __ATOMIC_RELEASE, __HIP_MEMORY_SCOPE_AGENT);
      const unsigned tgt = 8u*(unsigned)(t+1);
      while (__hip_atomic_load(cb, __ATOMIC_ACQUIRE, __HIP_MEMORY_SCOPE_AGENT) < tgt)
        __builtin_amdgcn_s_sleep(2);
    }
    __syncthreads();

    // ---- gather g partials (regular coalesced ull loads) -> error ----
    if (live) {
      float g0=0,g1=0,g2=0,g3=0;
      #pragma unroll
      for (int s2 = 0; s2 < 8; s2++) {
        ull v = *(const ull*)(Pq + (size_t)s2*PSTR + 2*tid);
        f16x2 A = uph((unsigned)v), Bv = uph((unsigned)(v >> 32));
        g0 += (float)A.x; g1 += (float)A.y; g2 += (float)Bv.x; g3 += (float)Bv.y;
      }
      float gs[4] = {g0,g1,g2,g3};
      float e[4];
      #pragma unroll
      for (int j = 0; j < 4; j++) {
        f16x2 bp = uph(be0_s[j][tid >> 1]);
        float bv = (tid & 1) ? (float)bp.y : (float)bp.x;
        e[j] = bv - xs1_s[j]*ftanh(gs[j]);
      }
      #pragma unroll
      for (int j = 0; j < 4; j++) {
        float other = __shfl_xor(e[j], 1, 64);
        if (!(tid & 1)) e_s[j][tid >> 1] = pkf16(e[j], other);
        float sj = wave_sum(e[j]*e[j]);
        if (lane == 0) esw_s[wave][j] = sj;
      }
    }
    // ---- slice 0: head flush for out row R (payload head region) ----
    {
      const int R = gt - 1;
      if (s == 0 && R >= t_out && tid >= 256 && tid < 384) {
        const int idx = tid - 256;            // [0,128)
        const int w = 1024 + idx;
        const int j = idx >> 5, cp = idx & 31;
        float s0 = 0.f, s1 = 0.f;
        #pragma unroll
        for (int s2 = 0; s2 < 8; s2++) {
          f16x2 hp = uph(Pq[(size_t)s2*PSTR + w]);
          s0 += (float)hp.x; s1 += (float)hp.y;
        }
        const int bj = (q & 7)*4 + j;
        size_t o = ((size_t)bj*SEQT + R)*64 + 2*cp;
        float2 cur = *(float2*)(out + o);
        cur.x += s0; cur.y += s1;
        *(float2*)(out + o) = cur;
      }
    }
    if (!live) continue;   // t==D: only payload store + barrier + head flush
    __syncthreads();       // e_s, esw_s ready

    // ---- surprise + W1 row-slice matvec ----
    if (tid < 4) {
      float tot = 0.f;
      #pragma unroll
      for (int w2 = 0; w2 < 8; w2++) tot += esw_s[w2][tid];
      float rel = fminf(sqrtf(tot)/xs1_s[tid], 4.0f);
      sp_s[tid] = 1.0f/(1.0f + __expf(-(rel - tau0v)/gmv));
    }
    {
      const int r = lane, oct = wave;
      float a0=0,a1=0,a2=0,a3=0;
      #pragma unroll
      for (int p = 0; p < 32; p++) {
        f16x2 w = uph(w1w[p]);
        float w0 = (float)w.x, w1v = (float)w.y;
        f16x2 e0 = uph(e_s[0][oct*32 + p]), e1 = uph(e_s[1][oct*32 + p]);
        f16x2 e2 = uph(e_s[2][oct*32 + p]), e3 = uph(e_s[3][oct*32 + p]);
        a0 += w0*(float)e0.x + w1v*(float)e0.y;
        a1 += w0*(float)e1.x + w1v*(float)e1.y;
        a2 += w0*(float)e2.x + w1v*(float)e2.y;
        a3 += w0*(float)e3.x + w1v*(float)e3.y;
      }
      red_s[oct][0][r] = a0; red_s[oct][1][r] = a1;
      red_s[oct][2][r] = a2; red_s[oct][3][r] = a3;
    }
    __syncthreads();

    // ---- h update ----
    if (tid < 256) {
      const int r = lane, j = wave;
      float ee = 0.f;
      #pragma unroll
      for (int o = 0; o < 8; o++) ee += red_s[o][j][r];
      const int bj = (q & 7)*4 + j;
      float be1v = (float)be1h[((size_t)bj*SEQT + gt)*512 + row0 + r];
      float sp = sp_s[j];
      float ih = 0.2f*h + 0.6f*be1v + 0.2f*sp*ee;
      h = h + a0v*(1.0f + sp)*(ftanh(ih) - h);
      float other = __shfl_xor(h, 1, 64);
      if (!(r & 1)) h2_s[j][r >> 1] = pkf16(h, other);
    }
    __syncthreads();       // h2_s new ready

    // ---- head partial for out row gt -> pay_s head region (sent next step) ----
    if (gt >= t_out && tid < 256) {
      const int c = lane, j = wave;
      float ha = 0.f;
      #pragma unroll
      for (int p = 0; p < 32; p++) {
        f16x2 w = uph(whh_s[c][p]);
        f16x2 hv = uph(h2_s[j][p]);
        ha += (float)w.x*(float)hv.x + (float)w.y*(float)hv.y;
      }
      float other = __shfl_xor(ha, 1, 64);
      if (!(c & 1)) pay_s[1024 + j*32 + (c >> 1)] = pkf16(ha, other);
    }
    __syncthreads();
  }
}

// ============================================================================
// FALLBACK (round-2, known-good 26.9ms, ~2.8MB ws)
// ============================================================================
__global__ __launch_bounds__(256) void rownorm_kernel(
    const float* __restrict__ X, float* __restrict__ xs, int M, int K)
{
  int wave = threadIdx.x >> 6, lane = threadIdx.x & 63;
  int m = blockIdx.x*4 + wave;
  if (m >= M) return;
  const float* row = X + (size_t)m*K;
  float acc = 0.f;
  for (int k = lane; k < K; k += 64) { float v = row[k]; acc += v*v; }
  acc = wave_sum(acc);
  if (lane == 0) xs[m] = fmaxf(sqrtf(acc), 1e-6f);
}

__global__ __launch_bounds__(256) void initout_kernel(
    float* __restrict__ out, const float* __restrict__ head_b)
{
  int i4 = blockIdx.x*256 + threadIdx.x;
  float4 v = ((const float4*)head_b)[i4 & 15];
  ((float4*)out)[i4] = v;
}

__global__ __launch_bounds__(256, 1) void recur_kernel(
    const float* __restrict__ feats, const float* __restrict__ B0,
    const float* __restrict__ C1, const float* __restrict__ B1,
    const float* __restrict__ W1, const float* __restrict__ ltc,
    const float* __restrict__ tau0p, const float* __restrict__ gammap,
    const float* __restrict__ head_w, const float* __restrict__ xs0v,
    float* __restrict__ out,
    float* __restrict__ PG, float* __restrict__ PB,
    float* __restrict__ BE, float* __restrict__ PS,
    unsigned int* __restrict__ cnt)
{
  const int wg = blockIdx.x;
  const int x = wg & 7, s = (wg >> 3) & 7, qq = wg >> 6;
  const int b = x*4 + qq;
  const int row0 = s*64;
  const int tid = threadIdx.x;
  const int r = tid >> 2, kc = tid & 3;
  const int wid = tid >> 6, lane = tid & 63;

  __shared__ float b0_s[64*84];
  __shared__ float whh_s[64*68];
  __shared__ float whb_s[64*68];
  __shared__ float er_s[512];
  __shared__ float ft_s[80];
  __shared__ float h_s[64];
  __shared__ float bo_s[64];
  __shared__ float bv_s[64];
  __shared__ float a0_s[64];
  __shared__ float red_s[4], red2_s[4];

  float c1c[128];
  unsigned b1p[64];
  float w1r[128];
  #pragma unroll
  for (int j = 0; j < 2; j++) {
    const float* src = C1 + (size_t)(tid + j*256)*512 + row0;
    #pragma unroll
    for (int k4 = 0; k4 < 16; k4++) {
      float4 v = *(const float4*)(src + 4*k4);
      c1c[j*64+4*k4]=v.x; c1c[j*64+4*k4+1]=v.y; c1c[j*64+4*k4+2]=v.z; c1c[j*64+4*k4+3]=v.w;
    }
  }
  #pragma unroll
  for (int j = 0; j < 2; j++) {
    const float* src = B1 + (size_t)(tid + j*256)*512 + row0;
    #pragma unroll
    for (int k4 = 0; k4 < 16; k4++) {
      float4 v = *(const float4*)(src + 4*k4);
      b1p[j*32+2*k4]   = pack_bf16(v.x, v.y);
      b1p[j*32+2*k4+1] = pack_bf16(v.z, v.w);
    }
  }
  {
    const float* src = W1 + (size_t)(row0 + r)*512;
    #pragma unroll
    for (int j4 = 0; j4 < 32; j4++) {
      const int f = kc*32 + ((j4 + kc) & 31);
      float4 v = *(const float4*)(src + 4*f);
      w1r[4*j4]=v.x; w1r[4*j4+1]=v.y; w1r[4*j4+2]=v.z; w1r[4*j4+3]=v.w;
    }
  }
  for (int i = tid; i < 5120; i += 256) {
    int rr = i/80, kk = i - rr*80;
    b0_s[rr*84 + kk] = B0[(size_t)(row0+rr)*80 + kk];
  }
  for (int i = tid; i < 4096; i += 256) {
    int c = i >> 6, j = i & 63;
    whh_s[c*68+j] = head_w[(size_t)c*1024 + row0 + j];
    whb_s[c*68+j] = head_w[(size_t)c*1024 + 512 + row0 + j];
  }
  if (tid < 64) {
    float xv = ltc[row0 + tid];
    float spl = (xv > 20.f) ? xv : log1pf(__expf(xv));
    a0_s[tid] = 0.1f / (1.0f + spl);
    h_s[tid] = 0.f;
  }
  const float tau0v = *tau0p, gmv = *gammap;
  unsigned int* cb = cnt + b*32;
  __syncthreads();

  for (int t = 0; t < SEQT; ++t) {
    const int par = t & 1;
    float* PGw = PG + (((size_t)par*BATCHN + b)*8 + s)*512;
    float* PBw = PB + (((size_t)par*BATCHN + b)*8 + s)*512;
    float* BEb = BE + ((size_t)par*BATCHN + b)*512;
    float* PSb = PS + ((size_t)par*BATCHN + b)*8;
    const size_t bt = (size_t)b*SEQT + t;

    if (tid < 80) ft_s[tid] = feats[bt*80 + tid];
    const float rxs0 = 1.0f / xs0v[bt];
    __syncthreads();

    float a = 0.f;
    #pragma unroll
    for (int j4 = 0; j4 < 5; j4++) {
      float4 bw = *(const float4*)(b0_s + r*84 + kc*20 + 4*j4);
      float4 fv = *(const float4*)(ft_s + kc*20 + 4*j4);
      a += bw.x*fv.x + bw.y*fv.y + bw.z*fv.z + bw.w*fv.w;
    }
    a += __shfl_xor(a, 1, 64); a += __shfl_xor(a, 2, 64);
    const float be0v = a * rxs0;
    if (kc == 0) { bo_s[r] = be0v; AT_ST(&BEb[row0 + r], be0v); }
    float sq = 0.25f*be0v*be0v;
    sq = wave_sum(sq);
    if (lane == 0) red_s[wid] = sq;
    __syncthreads();

    float pg0=0.f, pg1=0.f, pb0=0.f, pb1=0.f;
    #pragma unroll
    for (int k4 = 0; k4 < 16; k4++) {
      float4 hv = *(const float4*)(h_s + 4*k4);
      float4 ov = *(const float4*)(bo_s + 4*k4);
      pg0 += c1c[4*k4]*hv.x + c1c[4*k4+1]*hv.y + c1c[4*k4+2]*hv.z + c1c[4*k4+3]*hv.w;
      pg1 += c1c[64+4*k4]*hv.x + c1c[64+4*k4+1]*hv.y + c1c[64+4*k4+2]*hv.z + c1c[64+4*k4+3]*hv.w;
      unsigned p0 = b1p[2*k4], p1 = b1p[2*k4+1];
      unsigned q0 = b1p[32+2*k4], q1 = b1p[32+2*k4+1];
      pb0 += bf_lo(p0)*ov.x + bf_hi(p0)*ov.y + bf_lo(p1)*ov.z + bf_hi(p1)*ov.w;
      pb1 += bf_lo(q0)*ov.x + bf_hi(q0)*ov.y + bf_lo(q1)*ov.z + bf_hi(q1)*ov.w;
    }
    AT_ST(&PGw[tid], pg0); AT_ST(&PGw[tid+256], pg1);
    AT_ST(&PBw[tid], pb0); AT_ST(&PBw[tid+256], pb1);
    __syncthreads();

    if (tid == 0) {
      float ps = red_s[0]+red_s[1]+red_s[2]+red_s[3];
      AT_ST(&PSb[s], ps);
      __hip_atomic_fetch_add(cb, 1u, __ATOMIC_RELEASE, __HIP_MEMORY_SCOPE_AGENT);
      const unsigned tgt = 8u*(unsigned)(t+1);
      while (__hip_atomic_load(cb, __ATOMIC_ACQUIRE, __HIP_MEMORY_SCOPE_AGENT) < tgt)
        __builtin_amdgcn_s_sleep(1);
    }
    __syncthreads();

    const float* PGr = PG + ((size_t)par*BATCHN + b)*8*512;
    const float* PBr = PB + ((size_t)par*BATCHN + b)*8*512;
    float xsq = 0.f;
    #pragma unroll
    for (int s2 = 0; s2 < 8; s2++) xsq += AT_LD(&PSb[s2]);
    const float xs1 = fmaxf(sqrtf(xsq), 1e-6f);
    const float rxs1 = 1.0f / xs1;

    float gp0=0.f, gp1=0.f;
    #pragma unroll
    for (int s2 = 0; s2 < 8; s2++) {
      gp0 += AT_LD(&PGr[s2*512 + tid]);
      gp1 += AT_LD(&PGr[s2*512 + tid+256]);
    }
    const float bea = AT_LD(&BEb[tid]);
    const float beb = AT_LD(&BEb[tid+256]);
    const float e0 = bea - xs1*ftanh(gp0);
    const float e1 = beb - xs1*ftanh(gp1);
    er_s[tid] = e0; er_s[tid+256] = e1;
    float es = wave_sum(e0*e0 + e1*e1);
    if (lane == 0) red2_s[wid] = es;

    float pbv = AT_LD(&PBr[(2*kc)*512 + row0 + r]) + AT_LD(&PBr[(2*kc+1)*512 + row0 + r]);
    pbv += __shfl_xor(pbv, 1, 64); pbv += __shfl_xor(pbv, 2, 64);
    const float be1v = pbv * rxs1;
    if (kc == 0) bv_s[r] = be1v;
    __syncthreads();

    const float rel = fminf(sqrtf(red2_s[0]+red2_s[1]+red2_s[2]+red2_s[3]) * rxs1, 4.0f);
    const float sp = 1.0f/(1.0f + __expf(-(rel - tau0v)/gmv));

    float ee = 0.f;
    #pragma unroll
    for (int j4 = 0; j4 < 32; j4++) {
      const int f = kc*32 + ((j4 + kc) & 31);
      float4 ev = *(const float4*)(er_s + 4*f);
      ee += w1r[4*j4]*ev.x + w1r[4*j4+1]*ev.y + w1r[4*j4+2]*ev.z + w1r[4*j4+3]*ev.w;
    }
    ee += __shfl_xor(ee, 1, 64); ee += __shfl_xor(ee, 2, 64);

    const float hold = h_s[r];
    const float ih = 0.2f*hold + 0.6f*be1v + 0.2f*sp*ee;
    const float th = ftanh(ih);
    const float hn = hold + a0_s[r]*(1.0f + sp)*(th - hold);
    if (kc == 0) h_s[r] = hn;
    __syncthreads();

    {
      const int c = r; const int j0 = kc*16;
      float hacc = 0.f;
      #pragma unroll
      for (int j4 = 0; j4 < 4; j4++) {
        float4 hv4 = *(const float4*)(h_s  + j0 + 4*j4);
        float4 bv4 = *(const float4*)(bv_s + j0 + 4*j4);
        float4 wh  = *(const float4*)(whh_s + c*68 + j0 + 4*j4);
        float4 wb  = *(const float4*)(whb_s + c*68 + j0 + 4*j4);
        hacc += hv4.x*wh.x + hv4.y*wh.y + hv4.z*wh.z + hv4.w*wh.w
              + bv4.x*wb.x + bv4.y*wb.y + bv4.z*wb.z + bv4.w*wb.w;
      }
      hacc += __shfl_xor(hacc, 1, 64); hacc += __shfl_xor(hacc, 2, 64);
      if (kc == 0) atomicAdd(&out[bt*64 + c], hacc);
    }
  }
}

// ============================================================================

extern "C" void kernel_launch(void* const* d_in, const int* in_sizes, int n_in,
                              void* d_out, int out_size, void* d_ws, size_t ws_size,
                              hipStream_t stream)
{
  (void)in_sizes; (void)n_in; (void)out_size;
  const float* feats  = (const float*)d_in[0];
  const float* B0     = (const float*)d_in[2];
  const float* C1     = (const float*)d_in[7];
  const float* B1     = (const float*)d_in[8];
  const float* W1     = (const float*)d_in[9];
  const float* tau0_1 = (const float*)d_in[10];
  const float* gamma1 = (const float*)d_in[11];
  const float* ltc1   = (const float*)d_in[12];
  const float* head_w = (const float*)d_in[13];
  const float* head_b = (const float*)d_in[14];
  float* out = (float*)d_out;

  // ---- main-path ws: be1h 64MB | xs0w | xs1w | P 2.6MB | CNT ----
  _Float16* be1h = (_Float16*)d_ws;
  float* xs0w = (float*)(be1h + (size_t)BTROWS*HIDN);
  float* xs1w = xs0w + BTROWS;
  unsigned* P = (unsigned*)(xs1w + BTROWS);
  unsigned* CNT = P + (size_t)2*NQ*8*PSTR;
  size_t needed_main = (size_t)((char*)(CNT + NQ*32) - (char*)d_ws);   // ~67.5MB

  if (ws_size >= needed_main) {
    prep_kernel<<<BTROWS/PBM, 256, 0, stream>>>(feats, B0, B1, be1h, xs0w, xs1w);
    headbase_kernel<<<BTROWS/128, 256, 0, stream>>>(be1h, head_w + 512, out, head_b);
    hipMemsetAsync(CNT, 0, NQ*32*sizeof(unsigned), stream);
    void* args[] = { (void*)&feats, (void*)&B0, (void*)&C1, (void*)&W1,
                     (void*)&ltc1, (void*)&tau0_1, (void*)&gamma1, (void*)&head_w,
                     (void*)&be1h, (void*)&xs0w, (void*)&xs1w, (void*)&out,
                     (void*)&P, (void*)&CNT };
    hipError_t e = hipLaunchCooperativeKernel((void*)recur4_kernel, dim3(256), dim3(512),
                                              args, 0, stream);
    if (e != hipSuccess) {
      recur4_kernel<<<256, 512, 0, stream>>>(feats, B0, C1, W1, ltc1, tau0_1, gamma1,
                                             head_w, be1h, xs0w, xs1w, out, P, CNT);
    }
    return;
  }

  // ---- fallback (round-2 structure, ~2.8MB) ----
  float* PG  = (float*)d_ws;
  float* PB  = PG + (size_t)2*BATCHN*8*HIDN;
  float* BE  = PB + (size_t)2*BATCHN*8*HIDN;
  float* PS  = BE + (size_t)2*BATCHN*HIDN;
  float* xs0 = PS + (size_t)2*BATCHN*8;
  unsigned int* cnt = (unsigned int*)(xs0 + BTROWS);
  size_t needed_fb = (size_t)((char*)(cnt + BATCHN*32) - (char*)d_ws);
  if (ws_size < needed_fb) return;

  rownorm_kernel<<<BTROWS/4, 256, 0, stream>>>(feats, xs0, BTROWS, NMELS);
  initout_kernel<<<(BTROWS*NCLSN/4)/256, 256, 0, stream>>>(out, head_b);
  hipMemsetAsync(cnt, 0, BATCHN*32*sizeof(unsigned int), stream);
  void* args[] = { (void*)&feats, (void*)&B0, (void*)&C1, (void*)&B1, (void*)&W1,
                   (void*)&ltc1, (void*)&tau0_1, (void*)&gamma1, (void*)&head_w,
                   (void*)&xs0, (void*)&out,
                   (void*)&PG, (void*)&PB, (void*)&BE, (void*)&PS, (void*)&cnt };
  hipError_t e = hipLaunchCooperativeKernel((void*)recur_kernel, dim3(256), dim3(256),
                                            args, 0, stream);
  if (e != hipSuccess) {
    recur_kernel<<<256, 256, 0, stream>>>(feats, B0, C1, B1, W1, ltc1, tau0_1, gamma1,
                                          head_w, xs0, out, PG, PB, BE, PS, cnt);
  }
}

// Round 6
// 35182.373 us; speedup vs baseline: 1.2796x; 1.2796x over previous
//
#include <hip/hip_runtime.h>
#include <math.h>

#define BATCHN 32
#define SEQT   2048
#define NMELS  80
#define HIDN   512
#define NCLSN  64
#define BTROWS (BATCHN*SEQT)   // 65536
#define WUP    256
#define PGRP   2304            // u32 per (par,group) payload: 8*256 G + 8*32 BE

typedef _Float16 f16x2 __attribute__((ext_vector_type(2)));
typedef unsigned long long ull;

#if defined(__has_builtin)
#if __has_builtin(__builtin_amdgcn_fdot2)
#define FDOT2(a,b,c) __builtin_amdgcn_fdot2((a),(b),(c),false)
#endif
#endif
#ifndef FDOT2
#define FDOT2(a,b,c) ((float)(a).x*(float)(b).x + (float)(a).y*(float)(b).y + (c))
#endif

__device__ inline unsigned pkf16(float a, float b){
  union { f16x2 h; unsigned u; } c;
  c.h.x = (_Float16)a; c.h.y = (_Float16)b;
  return c.u;
}
__device__ inline f16x2 uph(unsigned u){
  union { unsigned u; f16x2 h; } c; c.u = u; return c.h;
}
__device__ inline float wave_sum(float v) {
  #pragma unroll
  for (int o = 32; o > 0; o >>= 1) v += __shfl_xor(v, o, 64);
  return v;
}
__device__ inline float ftanh(float x) {
  float ax = fabsf(x);
  float e = __expf(2.0f*ax);
  float t = 1.0f - 2.0f/(e + 1.0f);
  return copysignf(t, x);
}
__device__ inline unsigned pack_bf16(float a, float b) {
  union { float f; unsigned u; } ua, ub; ua.f = a; ub.f = b;
  unsigned lo = (ua.u + 0x7fffu + ((ua.u >> 16) & 1u)) >> 16;
  unsigned hi = (ub.u + 0x7fffu + ((ub.u >> 16) & 1u)) & 0xffff0000u;
  return (lo & 0xffffu) | hi;
}
__device__ inline float bf_lo(unsigned p) { union { unsigned u; float f; } c; c.u = p << 16; return c.f; }
__device__ inline float bf_hi(unsigned p) { union { unsigned u; float f; } c; c.u = p & 0xffff0000u; return c.f; }

#define AT_ST(p,v) __hip_atomic_store((p),(v),__ATOMIC_RELAXED,__HIP_MEMORY_SCOPE_AGENT)
#define AT_LD(p)   __hip_atomic_load((p),__ATOMIC_RELAXED,__HIP_MEMORY_SCOPE_AGENT)

// ============================================================================
// PREP (validated r3-r5): be1 (f16), xs0, xs1
// ============================================================================
#define PBM 32
__global__ __launch_bounds__(256) void prep_kernel(
    const float* __restrict__ feats, const float* __restrict__ B0,
    const float* __restrict__ B1,
    _Float16* __restrict__ be1h, float* __restrict__ xs0w, float* __restrict__ xs1w)
{
  __shared__ float fts[PBM*80];
  __shared__ _Float16 be0h[PBM*520];
  __shared__ float rxs0_s[PBM], rxs1_s[PBM];
  __shared__ float Bs[16*521];
  const int tid = threadIdx.x;
  const size_t m0 = (size_t)blockIdx.x * PBM;

  for (int i = tid; i < PBM*80; i += 256) {
    int r = i/80, k = i - r*80;
    fts[i] = feats[(m0+r)*80 + k];
  }
  __syncthreads();
  {
    int r = tid >> 3, kc = tid & 7;
    float s = 0.f;
    for (int k = kc*10; k < kc*10+10; k++) { float v = fts[r*80+k]; s += v*v; }
    s += __shfl_xor(s,1,64); s += __shfl_xor(s,2,64); s += __shfl_xor(s,4,64);
    float xs0v = fmaxf(sqrtf(s), 1e-6f);
    if (kc == 0) { xs0w[m0+r] = xs0v; rxs0_s[r] = 1.0f/xs0v; }
  }
  __syncthreads();
  {
    unsigned b0a[40], b0b[40];
    #pragma unroll
    for (int i = 0; i < 40; i++) {
      float2 v = *(const float2*)(B0 + (size_t)tid*80 + 2*i);
      b0a[i] = pkf16(v.x, v.y);
      float2 w = *(const float2*)(B0 + (size_t)(tid+256)*80 + 2*i);
      b0b[i] = pkf16(w.x, w.y);
    }
    for (int r = 0; r < PBM; r++) {
      float rx = rxs0_s[r];
      float a0 = 0.f, a1 = 0.f;
      #pragma unroll
      for (int i = 0; i < 40; i++) {
        float2 f = *(const float2*)(fts + r*80 + 2*i);
        f16x2 fa; fa.x = (_Float16)(f.x*rx); fa.y = (_Float16)(f.y*rx);
        a0 = FDOT2(uph(b0a[i]), fa, a0);
        a1 = FDOT2(uph(b0b[i]), fa, a1);
      }
      be0h[r*520 + tid]     = (_Float16)a0;
      be0h[r*520 + tid+256] = (_Float16)a1;
    }
  }
  __syncthreads();
  {
    int r = tid >> 3, kc = tid & 7;
    float s = 0.f;
    for (int k = kc*64; k < kc*64+64; k++) { float v = (float)be0h[r*520+k]; s += v*v; }
    s += __shfl_xor(s,1,64); s += __shfl_xor(s,2,64); s += __shfl_xor(s,4,64);
    float xs1v = fmaxf(sqrtf(s), 1e-6f);
    if (kc == 0) { xs1w[m0+r] = xs1v; rxs1_s[r] = 1.0f/xs1v; }
  }
  __syncthreads();
  const int tx = tid & 63, ty = tid >> 6;
  float acc[8][8] = {};
  for (int k0 = 0; k0 < 512; k0 += 16) {
    for (int nn = tid; nn < 512; nn += 256) {
      const float* src = B1 + (size_t)nn*512 + k0;
      #pragma unroll
      for (int q = 0; q < 4; q++) {
        float4 v = *(const float4*)(src + 4*q);
        Bs[(4*q+0)*521 + nn] = v.x; Bs[(4*q+1)*521 + nn] = v.y;
        Bs[(4*q+2)*521 + nn] = v.z; Bs[(4*q+3)*521 + nn] = v.w;
      }
    }
    __syncthreads();
    #pragma unroll
    for (int kk = 0; kk < 16; kk += 2) {
      float a0[8], a1[8];
      #pragma unroll
      for (int i = 0; i < 8; i++) {
        f16x2 p = *(const f16x2*)&be0h[(ty*8+i)*520 + k0 + kk];
        a0[i] = (float)p.x; a1[i] = (float)p.y;
      }
      float b0v[8], b1v[8];
      #pragma unroll
      for (int j = 0; j < 8; j++) {
        b0v[j] = Bs[kk*521 + tx*8+j];
        b1v[j] = Bs[(kk+1)*521 + tx*8+j];
      }
      #pragma unroll
      for (int i = 0; i < 8; i++)
        #pragma unroll
        for (int j = 0; j < 8; j++)
          acc[i][j] += a0[i]*b0v[j] + a1[i]*b1v[j];
    }
    __syncthreads();
  }
  #pragma unroll
  for (int i = 0; i < 8; i++) {
    int r = ty*8+i; float sc = rxs1_s[r];
    uint4 d;
    d.x = pkf16(acc[i][0]*sc, acc[i][1]*sc);
    d.y = pkf16(acc[i][2]*sc, acc[i][3]*sc);
    d.z = pkf16(acc[i][4]*sc, acc[i][5]*sc);
    d.w = pkf16(acc[i][6]*sc, acc[i][7]*sc);
    *(uint4*)(be1h + (m0+r)*512 + tx*8) = d;
  }
}

// ---- head base (validated): out = head_b + be1 @ head_w[:,512:]^T ----
__global__ __launch_bounds__(256) void headbase_kernel(
    const _Float16* __restrict__ A, const float* __restrict__ Bt,
    float* __restrict__ C, const float* __restrict__ bias)
{
  __shared__ float As[16][132];
  __shared__ float Bs[16][68];
  const int tid = threadIdx.x;
  const size_t m0 = (size_t)blockIdx.x * 128;
  const int tx = tid & 15, ty = tid >> 4;
  float acc[8][4] = {};
  for (int k0 = 0; k0 < 512; k0 += 16) {
    {
      int m = tid >> 1, kk2 = (tid*4) & 7;
      uint4 v = *(const uint4*)(A + (m0+m)*512 + k0 + kk2*2);
      f16x2 h0 = uph(v.x), h1 = uph(v.y), h2v = uph(v.z), h3 = uph(v.w);
      As[kk2*2+0][m] = (float)h0.x; As[kk2*2+1][m] = (float)h0.y;
      As[kk2*2+2][m] = (float)h1.x; As[kk2*2+3][m] = (float)h1.y;
      As[kk2*2+4][m] = (float)h2v.x; As[kk2*2+5][m] = (float)h2v.y;
      As[kk2*2+6][m] = (float)h3.x; As[kk2*2+7][m] = (float)h3.y;
    }
    {
      int n = tid >> 2, kq = tid & 3;
      float4 v = *(const float4*)(Bt + (size_t)n*1024 + k0 + kq*4);
      Bs[kq*4+0][n] = v.x; Bs[kq*4+1][n] = v.y;
      Bs[kq*4+2][n] = v.z; Bs[kq*4+3][n] = v.w;
    }
    __syncthreads();
    #pragma unroll
    for (int kk = 0; kk < 16; kk++) {
      float a[8], b[4];
      #pragma unroll
      for (int i = 0; i < 8; i++) a[i] = As[kk][ty*8+i];
      #pragma unroll
      for (int j = 0; j < 4; j++) b[j] = Bs[kk][tx*4+j];
      #pragma unroll
      for (int i = 0; i < 8; i++)
        #pragma unroll
        for (int j = 0; j < 4; j++) acc[i][j] += a[i]*b[j];
    }
    __syncthreads();
  }
  #pragma unroll
  for (int i = 0; i < 8; i++) {
    size_t m = m0 + ty*8 + i;
    float4 v;
    v.x = acc[i][0] + bias[tx*4+0];
    v.y = acc[i][1] + bias[tx*4+1];
    v.z = acc[i][2] + bias[tx*4+2];
    v.w = acc[i][3] + bias[tx*4+3];
    *(float4*)(C + m*64 + tx*4) = v;
  }
}

// ============================================================================
// RECUR v6: r2's proven step structure (8x64 slices, 1 seq/group, 256 thr,
// fp32 recurrent math) + 2x temporal chunking (512 WGs, 2/CU) + slim f16
// payload (prep provides be1/xs) + relaxed spin with ONE acquire per step.
// ============================================================================
__global__ __launch_bounds__(256, 2) void recur6_kernel(
    const float* __restrict__ feats, const float* __restrict__ B0,
    const float* __restrict__ C1, const float* __restrict__ W1,
    const float* __restrict__ ltc,
    const float* __restrict__ tau0p, const float* __restrict__ gammap,
    const float* __restrict__ head_w, const _Float16* __restrict__ be1h,
    const float* __restrict__ xs0w, const float* __restrict__ xs1w,
    float* __restrict__ out, unsigned* __restrict__ P,
    unsigned* __restrict__ CNT)
{
  const int wg = blockIdx.x;
  const int x = wg & 7, s = (wg >> 3) & 7, u = wg >> 6;
  const int p = x*8 + u;                 // group: its 8 slice-WGs share wg%8 (XCD)
  const int b = p & 31, chunk = p >> 5;  // 32 batches x 2 chunks
  const int t_begin = chunk ? (1024 - WUP) : 0;
  const int wfrom   = chunk ? 1024 : 0;
  const int D       = chunk ? (2048 - t_begin) : 1024;   // 1280 or 1024
  const int tid = threadIdx.x;
  const int r = tid >> 2, kc = tid & 3;
  const int wid = tid >> 6, lane = tid & 63;
  const int row0 = s*64;

  __shared__ float b0_s[64*84];      // B0 slice f32, pad 84 (r2-proven)
  __shared__ unsigned whh_s[64*34];  // head_w h-half slice, f16 pairs
  __shared__ float er_s[512];        // full error
  __shared__ float bef_s[512];       // full be0 (gathered)
  __shared__ float ft_s[80];
  __shared__ float h_s[64];          // own h slice
  __shared__ float bo_s[64];         // own be0 slice
  __shared__ float a0_s[64];
  __shared__ float red2_s[4];
  __shared__ float scal_s[1];

  // C1 column-slice fp32 (r2-proven layout): c1c[j*64+k] = C1[tid+j*256][row0+k]
  float c1c[128];
  #pragma unroll
  for (int j = 0; j < 2; j++) {
    const float* src = C1 + (size_t)(tid + j*256)*512 + row0;
    #pragma unroll
    for (int k4 = 0; k4 < 16; k4++) {
      float4 v = *(const float4*)(src + 4*k4);
      c1c[j*64+4*k4]=v.x; c1c[j*64+4*k4+1]=v.y; c1c[j*64+4*k4+2]=v.z; c1c[j*64+4*k4+3]=v.w;
    }
  }
  // W1 row-slice, f16 pairs, kc-staggered load order (static reg index)
  unsigned w1w[64];
  {
    const float* src = W1 + (size_t)(row0 + r)*512 + kc*128;
    #pragma unroll
    for (int i = 0; i < 64; i++) {
      const int p2 = (i + kc) & 63;
      float2 v = *(const float2*)(src + 2*p2);
      w1w[i] = pkf16(v.x, v.y);
    }
  }
  for (int i = tid; i < 5120; i += 256) {
    int rr = i/80, kk = i - rr*80;
    b0_s[rr*84 + kk] = B0[(size_t)(row0+rr)*80 + kk];
  }
  for (int i = tid; i < 64*32; i += 256) {
    int c = i >> 5, pj = i & 31;
    float2 v = *(const float2*)(head_w + (size_t)c*1024 + row0 + 2*pj);
    whh_s[c*34 + pj] = pkf16(v.x, v.y);
  }
  if (tid < 64) {
    float xv = ltc[row0 + tid];
    float spl = (xv > 20.f) ? xv : log1pf(__expf(xv));
    a0_s[tid] = 0.1f / (1.0f + spl);
    h_s[tid] = 0.f;
  }
  const float tau0v = *tau0p, gmv = *gammap;
  unsigned* cb = CNT + p*32;   // 128B-padded counter per group
  __syncthreads();

  for (int t = 0; t < D; ++t) {
    const int gt = t_begin + t;
    const int par = t & 1;
    unsigned* Pb = P + ((size_t)par*64 + p)*PGRP;
    const size_t bt = (size_t)b*SEQT + gt;

    if (tid < 80) ft_s[tid] = feats[bt*80 + tid];
    const float rxs0 = 1.0f / xs0w[bt];
    const float xs1v = xs1w[bt];
    const float bev = (float)be1h[bt*512 + row0 + r];  // prefetch for h-update
    __syncthreads();

    // ---- be0 slice: 4 threads/row x 20 feats (r2-proven) ----
    float a = 0.f;
    #pragma unroll
    for (int j4 = 0; j4 < 5; j4++) {
      float4 bw = *(const float4*)(b0_s + r*84 + kc*20 + 4*j4);
      float4 fv = *(const float4*)(ft_s + kc*20 + 4*j4);
      a += bw.x*fv.x + bw.y*fv.y + bw.z*fv.z + bw.w*fv.w;
    }
    a += __shfl_xor(a, 1, 64); a += __shfl_xor(a, 2, 64);
    const float be0v = a * rxs0;
    if (kc == 0) bo_s[r] = be0v;
    __syncthreads();   // bo_s ready

    // ---- C1 column partial over own h slice (fp32, r2-proven) ----
    float pg0 = 0.f, pg1 = 0.f;
    #pragma unroll
    for (int k4 = 0; k4 < 16; k4++) {
      float4 hv = *(const float4*)(h_s + 4*k4);
      pg0 += c1c[4*k4]*hv.x + c1c[4*k4+1]*hv.y + c1c[4*k4+2]*hv.z + c1c[4*k4+3]*hv.w;
      pg1 += c1c[64+4*k4]*hv.x + c1c[64+4*k4+1]*hv.y + c1c[64+4*k4+2]*hv.z + c1c[64+4*k4+3]*hv.w;
    }
    // regular coalesced payload stores (f16): G word tid = rows (tid, tid+256)
    Pb[s*256 + tid] = pkf16(pg0, pg1);
    if (tid < 32) Pb[2048 + s*32 + tid] = pkf16(bo_s[2*tid], bo_s[2*tid+1]);
    __syncthreads();   // all waves' stores drained (vmcnt0 before s_barrier)

    // ---- barrier: RELEASE add (wbl2 pushes dirty payload to IC);
    //      relaxed spin (L2-bypassing atomic loads); ONE acquire at exit ----
    if (tid == 0) {
      __hip_atomic_fetch_add(cb, 1u, __ATOMIC_RELEASE, __HIP_MEMORY_SCOPE_AGENT);
      const unsigned tgt = 8u*(unsigned)(t+1);
      while (AT_LD(cb) < tgt) __builtin_amdgcn_s_sleep(1);
      (void)__hip_atomic_load(cb, __ATOMIC_ACQUIRE, __HIP_MEMORY_SCOPE_AGENT);
    }
    __syncthreads();

    // ---- gather (regular coalesced loads; fresh after the single acquire) ----
    float g0 = 0.f, g1 = 0.f;
    #pragma unroll
    for (int s2 = 0; s2 < 8; s2++) {
      f16x2 v = uph(Pb[s2*256 + tid]);
      g0 += (float)v.x; g1 += (float)v.y;
    }
    {
      f16x2 w = uph(Pb[2048 + tid]);    // BE word tid -> be0[2tid, 2tid+1]
      bef_s[2*tid] = (float)w.x; bef_s[2*tid+1] = (float)w.y;
    }
    __syncthreads();   // bef_s ready
    const float e0 = bef_s[tid]     - xs1v*ftanh(g0);
    const float e1 = bef_s[tid+256] - xs1v*ftanh(g1);
    er_s[tid] = e0; er_s[tid+256] = e1;
    float es = wave_sum(e0*e0 + e1*e1);
    if (lane == 0) red2_s[wid] = es;
    __syncthreads();
    if (tid == 0) {
      float rel = fminf(sqrtf(red2_s[0]+red2_s[1]+red2_s[2]+red2_s[3]) / xs1v, 4.0f);
      scal_s[0] = 1.0f/(1.0f + __expf(-(rel - tau0v)/gmv));
    }
    __syncthreads();
    const float sp = scal_s[0];

    // ---- err_eff row-slice matvec (f16 weights, kc-staggered er reads) ----
    float ee = 0.f;
    #pragma unroll
    for (int i = 0; i < 64; i++) {
      const int p2 = (i + kc) & 63;
      f16x2 wv = uph(w1w[i]);
      float2 ev = *(const float2*)(er_s + kc*128 + 2*p2);
      ee += (float)wv.x*ev.x + (float)wv.y*ev.y;
    }
    ee += __shfl_xor(ee, 1, 64); ee += __shfl_xor(ee, 2, 64);

    // ---- h update (fp32) ----
    const float hold = h_s[r];
    const float ih = 0.2f*hold + 0.6f*bev + 0.2f*sp*ee;
    const float hn = hold + a0_s[r]*(1.0f + sp)*(ftanh(ih) - hold);
    if (kc == 0) h_s[r] = hn;
    __syncthreads();

    // ---- head h-half: out[b,gt,c] += sum_j h[j]*whh[c,j] (skip warm-up) ----
    if (gt >= wfrom) {
      const int c = r, j0 = kc*16;
      float ha = 0.f;
      #pragma unroll
      for (int pp = 0; pp < 8; pp++) {
        f16x2 wv = uph(whh_s[c*34 + kc*8 + pp]);
        ha += (float)wv.x*h_s[j0+2*pp] + (float)wv.y*h_s[j0+2*pp+1];
      }
      ha += __shfl_xor(ha, 1, 64); ha += __shfl_xor(ha, 2, 64);
      if (kc == 0) atomicAdd(&out[bt*64 + c], ha);
    }
    __syncthreads();
  }
}

// ============================================================================
// FALLBACK (round-2, known-good 26.9ms, ~2.8MB ws)
// ============================================================================
__global__ __launch_bounds__(256) void rownorm_kernel(
    const float* __restrict__ X, float* __restrict__ xs, int M, int K)
{
  int wave = threadIdx.x >> 6, lane = threadIdx.x & 63;
  int m = blockIdx.x*4 + wave;
  if (m >= M) return;
  const float* row = X + (size_t)m*K;
  float acc = 0.f;
  for (int k = lane; k < K; k += 64) { float v = row[k]; acc += v*v; }
  acc = wave_sum(acc);
  if (lane == 0) xs[m] = fmaxf(sqrtf(acc), 1e-6f);
}

__global__ __launch_bounds__(256) void initout_kernel(
    float* __restrict__ out, const float* __restrict__ head_b)
{
  int i4 = blockIdx.x*256 + threadIdx.x;
  float4 v = ((const float4*)head_b)[i4 & 15];
  ((float4*)out)[i4] = v;
}

__global__ __launch_bounds__(256, 1) void recur_kernel(
    const float* __restrict__ feats, const float* __restrict__ B0,
    const float* __restrict__ C1, const float* __restrict__ B1,
    const float* __restrict__ W1, const float* __restrict__ ltc,
    const float* __restrict__ tau0p, const float* __restrict__ gammap,
    const float* __restrict__ head_w, const float* __restrict__ xs0v,
    float* __restrict__ out,
    float* __restrict__ PG, float* __restrict__ PB,
    float* __restrict__ BE, float* __restrict__ PS,
    unsigned int* __restrict__ cnt)
{
  const int wg = blockIdx.x;
  const int x = wg & 7, s = (wg >> 3) & 7, qq = wg >> 6;
  const int b = x*4 + qq;
  const int row0 = s*64;
  const int tid = threadIdx.x;
  const int r = tid >> 2, kc = tid & 3;
  const int wid = tid >> 6, lane = tid & 63;

  __shared__ float b0_s[64*84];
  __shared__ float whh_s[64*68];
  __shared__ float whb_s[64*68];
  __shared__ float er_s[512];
  __shared__ float ft_s[80];
  __shared__ float h_s[64];
  __shared__ float bo_s[64];
  __shared__ float bv_s[64];
  __shared__ float a0_s[64];
  __shared__ float red_s[4], red2_s[4];

  float c1c[128];
  unsigned b1p[64];
  float w1r[128];
  #pragma unroll
  for (int j = 0; j < 2; j++) {
    const float* src = C1 + (size_t)(tid + j*256)*512 + row0;
    #pragma unroll
    for (int k4 = 0; k4 < 16; k4++) {
      float4 v = *(const float4*)(src + 4*k4);
      c1c[j*64+4*k4]=v.x; c1c[j*64+4*k4+1]=v.y; c1c[j*64+4*k4+2]=v.z; c1c[j*64+4*k4+3]=v.w;
    }
  }
  #pragma unroll
  for (int j = 0; j < 2; j++) {
    const float* src = B1 + (size_t)(tid + j*256)*512 + row0;
    #pragma unroll
    for (int k4 = 0; k4 < 16; k4++) {
      float4 v = *(const float4*)(src + 4*k4);
      b1p[j*32+2*k4]   = pack_bf16(v.x, v.y);
      b1p[j*32+2*k4+1] = pack_bf16(v.z, v.w);
    }
  }
  {
    const float* src = W1 + (size_t)(row0 + r)*512;
    #pragma unroll
    for (int j4 = 0; j4 < 32; j4++) {
      const int f = kc*32 + ((j4 + kc) & 31);
      float4 v = *(const float4*)(src + 4*f);
      w1r[4*j4]=v.x; w1r[4*j4+1]=v.y; w1r[4*j4+2]=v.z; w1r[4*j4+3]=v.w;
    }
  }
  for (int i = tid; i < 5120; i += 256) {
    int rr = i/80, kk = i - rr*80;
    b0_s[rr*84 + kk] = B0[(size_t)(row0+rr)*80 + kk];
  }
  for (int i = tid; i < 4096; i += 256) {
    int c = i >> 6, j = i & 63;
    whh_s[c*68+j] = head_w[(size_t)c*1024 + row0 + j];
    whb_s[c*68+j] = head_w[(size_t)c*1024 + 512 + row0 + j];
  }
  if (tid < 64) {
    float xv = ltc[row0 + tid];
    float spl = (xv > 20.f) ? xv : log1pf(__expf(xv));
    a0_s[tid] = 0.1f / (1.0f + spl);
    h_s[tid] = 0.f;
  }
  const float tau0v = *tau0p, gmv = *gammap;
  unsigned int* cb = cnt + b*32;
  __syncthreads();

  for (int t = 0; t < SEQT; ++t) {
    const int par = t & 1;
    float* PGw = PG + (((size_t)par*BATCHN + b)*8 + s)*512;
    float* PBw = PB + (((size_t)par*BATCHN + b)*8 + s)*512;
    float* BEb = BE + ((size_t)par*BATCHN + b)*512;
    float* PSb = PS + ((size_t)par*BATCHN + b)*8;
    const size_t bt = (size_t)b*SEQT + t;

    if (tid < 80) ft_s[tid] = feats[bt*80 + tid];
    const float rxs0 = 1.0f / xs0v[bt];
    __syncthreads();

    float a = 0.f;
    #pragma unroll
    for (int j4 = 0; j4 < 5; j4++) {
      float4 bw = *(const float4*)(b0_s + r*84 + kc*20 + 4*j4);
      float4 fv = *(const float4*)(ft_s + kc*20 + 4*j4);
      a += bw.x*fv.x + bw.y*fv.y + bw.z*fv.z + bw.w*fv.w;
    }
    a += __shfl_xor(a, 1, 64); a += __shfl_xor(a, 2, 64);
    const float be0v = a * rxs0;
    if (kc == 0) { bo_s[r] = be0v; AT_ST(&BEb[row0 + r], be0v); }
    float sq = 0.25f*be0v*be0v;
    sq = wave_sum(sq);
    if (lane == 0) red_s[wid] = sq;
    __syncthreads();

    float pg0=0.f, pg1=0.f, pb0=0.f, pb1=0.f;
    #pragma unroll
    for (int k4 = 0; k4 < 16; k4++) {
      float4 hv = *(const float4*)(h_s + 4*k4);
      float4 ov = *(const float4*)(bo_s + 4*k4);
      pg0 += c1c[4*k4]*hv.x + c1c[4*k4+1]*hv.y + c1c[4*k4+2]*hv.z + c1c[4*k4+3]*hv.w;
      pg1 += c1c[64+4*k4]*hv.x + c1c[64+4*k4+1]*hv.y + c1c[64+4*k4+2]*hv.z + c1c[64+4*k4+3]*hv.w;
      unsigned p0 = b1p[2*k4], p1 = b1p[2*k4+1];
      unsigned q0 = b1p[32+2*k4], q1 = b1p[32+2*k4+1];
      pb0 += bf_lo(p0)*ov.x + bf_hi(p0)*ov.y + bf_lo(p1)*ov.z + bf_hi(p1)*ov.w;
      pb1 += bf_lo(q0)*ov.x + bf_hi(q0)*ov.y + bf_lo(q1)*ov.z + bf_hi(q1)*ov.w;
    }
    AT_ST(&PGw[tid], pg0); AT_ST(&PGw[tid+256], pg1);
    AT_ST(&PBw[tid], pb0); AT_ST(&PBw[tid+256], pb1);
    __syncthreads();

    if (tid == 0) {
      float ps = red_s[0]+red_s[1]+red_s[2]+red_s[3];
      AT_ST(&PSb[s], ps);
      __hip_atomic_fetch_add(cb, 1u, __ATOMIC_RELEASE, __HIP_MEMORY_SCOPE_AGENT);
      const unsigned tgt = 8u*(unsigned)(t+1);
      while (__hip_atomic_load(cb, __ATOMIC_ACQUIRE, __HIP_MEMORY_SCOPE_AGENT) < tgt)
        __builtin_amdgcn_s_sleep(1);
    }
    __syncthreads();

    const float* PGr = PG + ((size_t)par*BATCHN + b)*8*512;
    const float* PBr = PB + ((size_t)par*BATCHN + b)*8*512;
    float xsq = 0.f;
    #pragma unroll
    for (int s2 = 0; s2 < 8; s2++) xsq += AT_LD(&PSb[s2]);
    const float xs1 = fmaxf(sqrtf(xsq), 1e-6f);
    const float rxs1 = 1.0f / xs1;

    float gp0=0.f, gp1=0.f;
    #pragma unroll
    for (int s2 = 0; s2 < 8; s2++) {
      gp0 += AT_LD(&PGr[s2*512 + tid]);
      gp1 += AT_LD(&PGr[s2*512 + tid+256]);
    }
    const float bea = AT_LD(&BEb[tid]);
    const float beb = AT_LD(&BEb[tid+256]);
    const float e0 = bea - xs1*ftanh(gp0);
    const float e1 = beb - xs1*ftanh(gp1);
    er_s[tid] = e0; er_s[tid+256] = e1;
    float es = wave_sum(e0*e0 + e1*e1);
    if (lane == 0) red2_s[wid] = es;

    float pbv = AT_LD(&PBr[(2*kc)*512 + row0 + r]) + AT_LD(&PBr[(2*kc+1)*512 + row0 + r]);
    pbv += __shfl_xor(pbv, 1, 64); pbv += __shfl_xor(pbv, 2, 64);
    const float be1v = pbv * rxs1;
    if (kc == 0) bv_s[r] = be1v;
    __syncthreads();

    const float rel = fminf(sqrtf(red2_s[0]+red2_s[1]+red2_s[2]+red2_s[3]) * rxs1, 4.0f);
    const float sp = 1.0f/(1.0f + __expf(-(rel - tau0v)/gmv));

    float ee = 0.f;
    #pragma unroll
    for (int j4 = 0; j4 < 32; j4++) {
      const int f = kc*32 + ((j4 + kc) & 31);
      float4 ev = *(const float4*)(er_s + 4*f);
      ee += w1r[4*j4]*ev.x + w1r[4*j4+1]*ev.y + w1r[4*j4+2]*ev.z + w1r[4*j4+3]*ev.w;
    }
    ee += __shfl_xor(ee, 1, 64); ee += __shfl_xor(ee, 2, 64);

    const float hold = h_s[r];
    const float ih = 0.2f*hold + 0.6f*be1v + 0.2f*sp*ee;
    const float th = ftanh(ih);
    const float hn = hold + a0_s[r]*(1.0f + sp)*(th - hold);
    if (kc == 0) h_s[r] = hn;
    __syncthreads();

    {
      const int c = r; const int j0 = kc*16;
      float hacc = 0.f;
      #pragma unroll
      for (int j4 = 0; j4 < 4; j4++) {
        float4 hv4 = *(const float4*)(h_s  + j0 + 4*j4);
        float4 bv4 = *(const float4*)(bv_s + j0 + 4*j4);
        float4 wh  = *(const float4*)(whh_s + c*68 + j0 + 4*j4);
        float4 wb  = *(const float4*)(whb_s + c*68 + j0 + 4*j4);
        hacc += hv4.x*wh.x + hv4.y*wh.y + hv4.z*wh.z + hv4.w*wh.w
              + bv4.x*wb.x + bv4.y*wb.y + bv4.z*wb.z + bv4.w*wb.w;
      }
      hacc += __shfl_xor(hacc, 1, 64); hacc += __shfl_xor(hacc, 2, 64);
      if (kc == 0) atomicAdd(&out[bt*64 + c], hacc);
    }
  }
}

// ============================================================================

extern "C" void kernel_launch(void* const* d_in, const int* in_sizes, int n_in,
                              void* d_out, int out_size, void* d_ws, size_t ws_size,
                              hipStream_t stream)
{
  (void)in_sizes; (void)n_in; (void)out_size;
  const float* feats  = (const float*)d_in[0];
  const float* B0     = (const float*)d_in[2];
  const float* C1     = (const float*)d_in[7];
  const float* B1     = (const float*)d_in[8];
  const float* W1     = (const float*)d_in[9];
  const float* tau0_1 = (const float*)d_in[10];
  const float* gamma1 = (const float*)d_in[11];
  const float* ltc1   = (const float*)d_in[12];
  const float* head_w = (const float*)d_in[13];
  const float* head_b = (const float*)d_in[14];
  float* out = (float*)d_out;

  // ---- main-path ws: be1h 64MB | xs0w | xs1w | P 1.2MB | CNT ----
  _Float16* be1h = (_Float16*)d_ws;
  float* xs0w = (float*)(be1h + (size_t)BTROWS*HIDN);
  float* xs1w = xs0w + BTROWS;
  unsigned* P = (unsigned*)(xs1w + BTROWS);
  unsigned* CNT = P + (size_t)2*64*PGRP;
  size_t needed_main = (size_t)((char*)(CNT + 64*32) - (char*)d_ws);   // ~66MB

  if (ws_size >= needed_main) {
    prep_kernel<<<BTROWS/PBM, 256, 0, stream>>>(feats, B0, B1, be1h, xs0w, xs1w);
    headbase_kernel<<<BTROWS/128, 256, 0, stream>>>(be1h, head_w + 512, out, head_b);
    hipMemsetAsync(CNT, 0, 64*32*sizeof(unsigned), stream);
    void* args[] = { (void*)&feats, (void*)&B0, (void*)&C1, (void*)&W1,
                     (void*)&ltc1, (void*)&tau0_1, (void*)&gamma1, (void*)&head_w,
                     (void*)&be1h, (void*)&xs0w, (void*)&xs1w, (void*)&out,
                     (void*)&P, (void*)&CNT };
    hipError_t e = hipLaunchCooperativeKernel((void*)recur6_kernel, dim3(512), dim3(256),
                                              args, 0, stream);
    if (e != hipSuccess) {
      // plain launch: 512 WGs at 2/CU fit the 256-CU device (co-resident in practice)
      recur6_kernel<<<512, 256, 0, stream>>>(feats, B0, C1, W1, ltc1, tau0_1, gamma1,
                                             head_w, be1h, xs0w, xs1w, out, P, CNT);
    }
    return;
  }

  // ---- fallback (round-2 structure, ~2.8MB) ----
  float* PG  = (float*)d_ws;
  float* PB  = PG + (size_t)2*BATCHN*8*HIDN;
  float* BE  = PB + (size_t)2*BATCHN*8*HIDN;
  float* PS  = BE + (size_t)2*BATCHN*HIDN;
  float* xs0 = PS + (size_t)2*BATCHN*8;
  unsigned int* cnt = (unsigned int*)(xs0 + BTROWS);
  size_t needed_fb = (size_t)((char*)(cnt + BATCHN*32) - (char*)d_ws);
  if (ws_size < needed_fb) return;

  rownorm_kernel<<<BTROWS/4, 256, 0, stream>>>(feats, xs0, BTROWS, NMELS);
  initout_kernel<<<(BTROWS*NCLSN/4)/256, 256, 0, stream>>>(out, head_b);
  hipMemsetAsync(cnt, 0, BATCHN*32*sizeof(unsigned int), stream);
  void* args[] = { (void*)&feats, (void*)&B0, (void*)&C1, (void*)&B1, (void*)&W1,
                   (void*)&ltc1, (void*)&tau0_1, (void*)&gamma1, (void*)&head_w,
                   (void*)&xs0, (void*)&out,
                   (void*)&PG, (void*)&PB, (void*)&BE, (void*)&PS, (void*)&cnt };
  hipError_t e = hipLaunchCooperativeKernel((void*)recur_kernel, dim3(256), dim3(256),
                                            args, 0, stream);
  if (e != hipSuccess) {
    recur_kernel<<<256, 256, 0, stream>>>(feats, B0, C1, B1, W1, ltc1, tau0_1, gamma1,
                                          head_w, xs0, out, PG, PB, BE, PS, cnt);
  }
}